// Round 8
// baseline (615.348 us; speedup 1.0000x reference)
//
#include <hip/hip_runtime.h>
#include <cstdint>
#include <cstddef>

#define T_TOK 4096
#define HIDDIM 2560
#define NH 8
#define NKV 4
#define HD 256
#define SEQ 2048
#define NBATCH 2
#define WIN 1024
#define NQKV 4096          // (8+2*4)*256
#define QSCALE 0.0625f     // 256^-0.5

typedef unsigned short u16;
typedef __attribute__((ext_vector_type(8))) __bf16 bf16x8;
typedef __attribute__((ext_vector_type(8))) u16 u16x8;
typedef __attribute__((ext_vector_type(4))) float f32x4;

__device__ __forceinline__ u16 f2bf(float f) {
  union { float f; uint32_t u; } x{f};
  uint32_t r = x.u + 0x7FFFu + ((x.u >> 16) & 1u);
  return (u16)(r >> 16);
}
__device__ __forceinline__ float bf2f(u16 h) {
  union { uint32_t u; float f; } x{((uint32_t)h) << 16};
  return x.f;
}
__device__ __forceinline__ void gload_lds16(const void* g, void* l) {
  __builtin_amdgcn_global_load_lds((const __attribute__((address_space(1))) unsigned int*)g,
                                   (__attribute__((address_space(3))) unsigned int*)l, 16, 0, 0);
}
template <int N>
__device__ __forceinline__ void vmcnt_wait() {
  if constexpr (N >= 8) asm volatile("s_waitcnt vmcnt(8)" ::: "memory");
  else if constexpr (N == 6) asm volatile("s_waitcnt vmcnt(6)" ::: "memory");
  else if constexpr (N == 4) asm volatile("s_waitcnt vmcnt(4)" ::: "memory");
  else if constexpr (N == 3) asm volatile("s_waitcnt vmcnt(3)" ::: "memory");
  else asm volatile("s_waitcnt vmcnt(0)" ::: "memory");
}

// ---------------- fp32 -> bf16 convert ----------------
__global__ void cvt_bf16(const float* __restrict__ in, u16* __restrict__ out, int n8) {
  int i = blockIdx.x * 256 + threadIdx.x;
  if (i >= n8) return;
  const f32x4* p = (const f32x4*)(in + (size_t)i * 8);
  f32x4 a = p[0], b = p[1];
  u16 o[8];
  o[0] = f2bf(a[0]); o[1] = f2bf(a[1]); o[2] = f2bf(a[2]); o[3] = f2bf(a[3]);
  o[4] = f2bf(b[0]); o[5] = f2bf(b[1]); o[6] = f2bf(b[2]); o[7] = f2bf(b[3]);
  *(u16x8*)(out + (size_t)i * 8) = *(const u16x8*)o;
}

// ---------------- GEMM 256x{256|128} tile, BK=32, 4-buffer counted-vmcnt pipeline
template <int M, int N, int K, int BN, int OUTBF16>
__global__ __launch_bounds__(512, 2) void gemm256(const u16* __restrict__ A,
                                                  const u16* __restrict__ Bt,
                                                  void* __restrict__ Cp) {
  constexpr int NT = K / 32;
  constexpr int BCH = BN * 4;
  constexpr int LPT = (1024 + BCH) / 512;
  constexpr int NREP = BN / 64;
  constexpr int BUFB = 16384 + BN * 64;
  __shared__ char smem[4 * BUFB];

  const int tid = threadIdx.x, lane = tid & 63, w = tid >> 6;
  const int wr = w >> 2, wc = w & 3, hi = lane >> 4, lo = lane & 15;
  const int hi16 = hi * 16;
  constexpr int TOT = (M / 256) * (N / BN);
  const int bid = blockIdx.x;
  const int wg = (bid & 7) * (TOT / 8) + (bid >> 3);
  const int m0 = (wg / (N / BN)) * 256;
  const int n0 = (wg % (N / BN)) * BN;

  f32x4 acc[8][NREP] = {};

  auto stage = [&](int tt, int bb) {
    const int k0 = tt * 32;
    char* base = smem + bb * BUFB;
#pragma unroll
    for (int it = 0; it < 2; ++it) {
      int c = tid + it * 512;
      int r = (c >> 2) ^ ((c >> 4) & 1);
      int h = (c & 3) ^ (r & 3);
      gload_lds16(A + (size_t)(m0 + r) * K + k0 + h * 8, base + c * 16);
    }
#pragma unroll
    for (int it = 0; it < BCH / 512; ++it) {
      int c = tid + it * 512;
      int r = (c >> 2) ^ ((c >> 4) & 1);
      int h = (c & 3) ^ (r & 3);
      gload_lds16(Bt + (size_t)(n0 + r) * K + k0 + h * 8, base + 16384 + c * 16);
    }
  };
  auto body = [&](int bb) {
    char* base = smem + bb * BUFB;
    bf16x8 a[8], b[NREP];
#pragma unroll
    for (int mi = 0; mi < 8; ++mi) {
      int r = wr * 128 + mi * 16 + lo;
      a[mi] = *(const bf16x8*)(base + ((r * 64 + hi16) ^ ((r & 7) << 4)));
    }
#pragma unroll
    for (int ni = 0; ni < NREP; ++ni) {
      int r = wc * (BN / 4) + ni * 16 + lo;
      b[ni] = *(const bf16x8*)(base + 16384 + ((r * 64 + hi16) ^ ((r & 7) << 4)));
    }
    __builtin_amdgcn_s_setprio(1);
#pragma unroll
    for (int mi = 0; mi < 8; ++mi)
#pragma unroll
      for (int ni = 0; ni < NREP; ++ni)
        acc[mi][ni] = __builtin_amdgcn_mfma_f32_16x16x32_bf16(a[mi], b[ni], acc[mi][ni], 0, 0, 0);
    __builtin_amdgcn_s_setprio(0);
  };

  stage(0, 0); stage(1, 1); stage(2, 2);
  vmcnt_wait<2 * LPT>();
  __builtin_amdgcn_s_barrier();
  int t = 0;
  for (; t < NT - 3; ++t) {
    stage(t + 3, (t + 3) & 3);
    body(t & 3);
    vmcnt_wait<2 * LPT>();
    __builtin_amdgcn_s_barrier();
  }
  body(t & 3); vmcnt_wait<LPT>(); __builtin_amdgcn_s_barrier(); ++t;
  body(t & 3); vmcnt_wait<0>();   __builtin_amdgcn_s_barrier(); ++t;
  body(t & 3);

#pragma unroll
  for (int mi = 0; mi < 8; ++mi)
#pragma unroll
    for (int ni = 0; ni < NREP; ++ni) {
      int row = m0 + wr * 128 + mi * 16 + hi * 4;
      int col = n0 + wc * (BN / 4) + ni * 16 + lo;
#pragma unroll
      for (int r = 0; r < 4; ++r) {
        if (OUTBF16)
          ((u16*)Cp)[(size_t)(row + r) * N + col] = f2bf(acc[mi][ni][r]);
        else
          ((float*)Cp)[(size_t)(row + r) * N + col] = acc[mi][ni][r];
      }
    }
}

// ---------------- fused RMSNorm + RoPE for q,k (scale folded into q) ----------------
__global__ void norm_rope(const u16* __restrict__ qkv, const float* __restrict__ cosb,
                          const float* __restrict__ sinb, const float* __restrict__ qw,
                          const float* __restrict__ kw, u16* __restrict__ qn,
                          u16* __restrict__ kn) {
  int gw = blockIdx.x * 4 + (threadIdx.x >> 6);
  int lane = threadIdx.x & 63;
  int t = gw / 12, hh = gw % 12;
  const u16* x = qkv + (size_t)t * NQKV + hh * HD;
  int d = lane * 2;
  float x1a = bf2f(x[d]), x1b = bf2f(x[d + 1]);
  float x2a = bf2f(x[d + 128]), x2b = bf2f(x[d + 129]);
  float ss = x1a * x1a + x1b * x1b + x2a * x2a + x2b * x2b;
#pragma unroll
  for (int off = 1; off < 64; off <<= 1) ss += __shfl_xor(ss, off, 64);
  float inv = rsqrtf(ss * (1.0f / 256.0f) + 1e-6f);
  const float* wp = (hh < 8) ? qw : kw;
  float c0 = cosb[t * 128 + d], c1 = cosb[t * 128 + d + 1];
  float s0 = sinb[t * 128 + d], s1 = sinb[t * 128 + d + 1];
  float sc = (hh < 8) ? QSCALE : 1.0f;
  float y1a = x1a * inv * wp[d], y1b = x1b * inv * wp[d + 1];
  float y2a = x2a * inv * wp[d + 128], y2b = x2b * inv * wp[d + 129];
  float o1a = (y1a * c0 - y2a * s0) * sc, o1b = (y1b * c1 - y2b * s1) * sc;
  float o2a = (y2a * c0 + y1a * s0) * sc, o2b = (y2b * c1 + y1b * s1) * sc;
  u16* o = (hh < 8) ? (qn + ((size_t)t * 8 + hh) * HD) : (kn + ((size_t)t * 4 + (hh - 8)) * HD);
  ushort2 lo2, hi2;
  lo2.x = f2bf(o1a); lo2.y = f2bf(o1b);
  hi2.x = f2bf(o2a); hi2.y = f2bf(o2b);
  *(ushort2*)&o[d] = lo2;
  *(ushort2*)&o[d + 128] = hi2;
}

// ---------------- V transpose: qkv v-slice -> vt[b][kv][d][s] ----------------
__global__ void vtransp(const u16* __restrict__ qkv, u16* __restrict__ vt) {
  const int b = blockIdx.y >> 2, kv = blockIdx.y & 3;
  const int s0 = blockIdx.x * 64;
  const int t = threadIdx.x;
  __shared__ u16 tile[64 * 64];
  for (int d0 = 0; d0 < 256; d0 += 64) {
#pragma unroll
    for (int it = 0; it < 2; ++it) {
      int c = t + it * 256;
      int sr = c >> 3, dc = (c & 7) * 8;
      bf16x8 v = *(const bf16x8*)&qkv[(size_t)(b * SEQ + s0 + sr) * NQKV + 3072 + kv * HD + d0 + dc];
      *(bf16x8*)((char*)tile + ((sr * 128 + dc * 2) ^ ((sr & 7) << 4))) = v;
    }
    __syncthreads();
#pragma unroll
    for (int it = 0; it < 2; ++it) {
      int c = t + it * 256;
      int dr = c >> 3, sc0 = (c & 7) * 8;
      union { u16 a[8]; bf16x8 v; } u;
#pragma unroll
      for (int j = 0; j < 8; ++j) {
        int s = sc0 + j;
        u.a[j] = *(const u16*)((char*)tile + ((s * 128 + dr * 2) ^ ((s & 7) << 4)));
      }
      *(bf16x8*)&vt[((size_t)(b * 4 + kv) * 256 + d0 + dr) * SEQ + s0 + sc0] = u.v;
    }
    __syncthreads();
  }
}

// ---------------- flash attention, sliding window, GQA ----------------
// KVBLK=64, async reg-staged prefetch (T14): issue next tile's global loads
// after QK^T, ds_write after the post-PV barrier. Only first/diagonal tiles
// need masking (middle tiles: j<i and i-j<=1023 provably hold).
__global__ __launch_bounds__(256, 2) void attn_fwd(const u16* __restrict__ qn,
                                                   const u16* __restrict__ kn,
                                                   const u16* __restrict__ vt,
                                                   u16* __restrict__ aout) {
  const int qt = blockIdx.x * 64, h = blockIdx.y, b = blockIdx.z;
  const int kvh = h >> 1;
  const int t = threadIdx.x, lane = t & 63, w = t >> 6, hi = lane >> 4, lo = lane & 15;
  __shared__ u16 Ks[64 * 256];    // [k][d], row 512B, swz byte^((k&7)<<4)
  __shared__ u16 Vs[256 * 64];    // [d][k], row 128B, swz byte^((d&7)<<4)
  __shared__ u16 Ps[4][16 * 64];  // per-wave [q][k], row 128B, swz byte^((q&7)<<4)

  bf16x8 qf[8];
  const int qrow = qt + w * 16 + lo;
#pragma unroll
  for (int dd = 0; dd < 8; ++dd)
    qf[dd] = *(const bf16x8*)&qn[((size_t)(b * SEQ + qrow) * 8 + h) * HD + dd * 32 + hi * 8];

  f32x4 oacc[16] = {};
  float mrow[4] = {-3e38f, -3e38f, -3e38f, -3e38f};
  float lrow[4] = {0.f, 0.f, 0.f, 0.f};
  const int kstart = qt >= WIN ? qt - WIN : 0;
  const int irow = qt + w * 16 + hi * 4;

  bf16x8 kreg[8], vreg[8];
  auto ldK = [&](int kt2) {
#pragma unroll
    for (int it = 0; it < 8; ++it) {
      int c = t + it * 256;
      kreg[it] = *(const bf16x8*)&kn[((size_t)(b * SEQ + kt2 + (c >> 5)) * 4 + kvh) * HD + (c & 31) * 8];
    }
  };
  auto ldV = [&](int kt2) {
#pragma unroll
    for (int it = 0; it < 8; ++it) {
      int c = t + it * 256;
      vreg[it] = *(const bf16x8*)&vt[((size_t)(b * 4 + kvh) * 256 + (c >> 3)) * SEQ + kt2 + (c & 7) * 8];
    }
  };
  auto stK = [&]() {
#pragma unroll
    for (int it = 0; it < 8; ++it) {
      int c = t + it * 256, kr = c >> 5;
      *(bf16x8*)((char*)Ks + ((kr * 512 + (c & 31) * 16) ^ ((kr & 7) << 4))) = kreg[it];
    }
  };
  auto stV = [&]() {
#pragma unroll
    for (int it = 0; it < 8; ++it) {
      int c = t + it * 256, dr = c >> 3;
      *(bf16x8*)((char*)Vs + ((dr * 128 + (c & 7) * 16) ^ ((dr & 7) << 4))) = vreg[it];
    }
  };

  ldK(kstart); ldV(kstart);
  stK(); stV();
  __syncthreads();

  for (int kt = kstart; kt <= qt; kt += 64) {
    // QK^T: S[q=hi*4+r][key=kk*16+lo]
    f32x4 sacc[4];
#pragma unroll
    for (int kk = 0; kk < 4; ++kk) {
      f32x4 sa = {0.f, 0.f, 0.f, 0.f};
      int krow = kk * 16 + lo;
#pragma unroll
      for (int dd = 0; dd < 8; ++dd) {
        bf16x8 kf = *(const bf16x8*)((char*)Ks + ((krow * 512 + (dd * 32 + hi * 8) * 2) ^ ((krow & 7) << 4)));
        sa = __builtin_amdgcn_mfma_f32_16x16x32_bf16(qf[dd], kf, sa, 0, 0, 0);
      }
      sacc[kk] = sa;
    }
    // prefetch next tile into regs (latency hides under softmax+PV)
    const bool more = (kt + 64) <= qt;
    if (more) { ldK(kt + 64); ldV(kt + 64); }
    // mask (only first/diagonal tiles) + online softmax
    const bool needmask = (kt == qt) || (qt >= WIN && kt == kstart);
    float tmax[4] = {-3e38f, -3e38f, -3e38f, -3e38f};
    if (needmask) {
#pragma unroll
      for (int kk = 0; kk < 4; ++kk)
#pragma unroll
        for (int r = 0; r < 4; ++r) {
          int i = irow + r, j = kt + kk * 16 + lo;
          bool ok = (j <= i) && (i - j < WIN);
          float sv = ok ? sacc[kk][r] : -3e38f;
          sacc[kk][r] = sv;
          tmax[r] = fmaxf(tmax[r], sv);
        }
    } else {
#pragma unroll
      for (int kk = 0; kk < 4; ++kk)
#pragma unroll
        for (int r = 0; r < 4; ++r) tmax[r] = fmaxf(tmax[r], sacc[kk][r]);
    }
#pragma unroll
    for (int off = 1; off < 16; off <<= 1)
#pragma unroll
      for (int r = 0; r < 4; ++r) tmax[r] = fmaxf(tmax[r], __shfl_xor(tmax[r], off, 64));
    float scl[4], tsum[4];
#pragma unroll
    for (int r = 0; r < 4; ++r) {
      float mnew = fmaxf(mrow[r], tmax[r]);
      scl[r] = __expf(mrow[r] - mnew);
      mrow[r] = mnew;
      tsum[r] = 0.f;
    }
    float pe[4][4];
#pragma unroll
    for (int kk = 0; kk < 4; ++kk)
#pragma unroll
      for (int r = 0; r < 4; ++r) {
        float sv = sacc[kk][r];
        float p = (sv <= -1e37f) ? 0.f : __expf(sv - mrow[r]);
        pe[kk][r] = p;
        tsum[r] += p;
      }
#pragma unroll
    for (int off = 1; off < 16; off <<= 1)
#pragma unroll
      for (int r = 0; r < 4; ++r) tsum[r] += __shfl_xor(tsum[r], off, 64);
#pragma unroll
    for (int r = 0; r < 4; ++r) lrow[r] = lrow[r] * scl[r] + tsum[r];
#pragma unroll
    for (int dt = 0; dt < 16; ++dt)
#pragma unroll
      for (int r = 0; r < 4; ++r) oacc[dt][r] *= scl[r];
    // write P to per-wave LDS (same-wave write->read, no barrier needed)
#pragma unroll
    for (int kk = 0; kk < 4; ++kk)
#pragma unroll
      for (int r = 0; r < 4; ++r) {
        int q = hi * 4 + r, cc = kk * 16 + lo;
        *(u16*)((char*)&Ps[w][0] + ((q * 128 + cc * 2) ^ ((q & 7) << 4))) = f2bf(pe[kk][r]);
      }
    // PV: A = P (q=lo rows), B = Vs (d rows), accumulate over 2 k-slices
    bf16x8 pf0 = *(const bf16x8*)((char*)&Ps[w][0] + ((lo * 128 + (hi * 8) * 2) ^ ((lo & 7) << 4)));
    bf16x8 pf1 = *(const bf16x8*)((char*)&Ps[w][0] + ((lo * 128 + (32 + hi * 8) * 2) ^ ((lo & 7) << 4)));
#pragma unroll
    for (int dt = 0; dt < 16; ++dt) {
      int d = dt * 16 + lo;
      bf16x8 vf0 = *(const bf16x8*)((char*)Vs + ((d * 128 + (hi * 8) * 2) ^ ((d & 7) << 4)));
      bf16x8 vf1 = *(const bf16x8*)((char*)Vs + ((d * 128 + (32 + hi * 8) * 2) ^ ((d & 7) << 4)));
      oacc[dt] = __builtin_amdgcn_mfma_f32_16x16x32_bf16(pf0, vf0, oacc[dt], 0, 0, 0);
      oacc[dt] = __builtin_amdgcn_mfma_f32_16x16x32_bf16(pf1, vf1, oacc[dt], 0, 0, 0);
    }
    if (more) {
      __syncthreads();   // all waves done reading Ks/Vs
      stK(); stV();      // write prefetched tile (compiler waits vmcnt)
      __syncthreads();   // new tile visible
    }
  }
  // epilogue
#pragma unroll
  for (int dt = 0; dt < 16; ++dt)
#pragma unroll
    for (int r = 0; r < 4; ++r) {
      int i = irow + r;
      aout[(size_t)(b * SEQ + i) * 2048 + h * HD + dt * 16 + lo] = f2bf(oacc[dt][r] / lrow[r]);
    }
}

extern "C" void kernel_launch(void* const* d_in, const int* in_sizes, int n_in,
                              void* d_out, int out_size, void* d_ws, size_t ws_size,
                              hipStream_t stream) {
  const float* hs = (const float*)d_in[0];
  const float* cosb = (const float*)d_in[1];
  const float* sinb = (const float*)d_in[2];
  const float* wqkv = (const float*)d_in[3];
  const float* qw = (const float*)d_in[4];
  const float* kw = (const float*)d_in[5];
  const float* wo = (const float*)d_in[6];
  char* ws = (char*)d_ws;
  u16* hs_b = (u16*)(ws);                   // 20.97 MB   [dead after GEMM1]
  u16* wqkv_b = (u16*)(ws + 20971520);      // 20.97 MB   [dead after GEMM1]
  u16* wo_b = (u16*)(ws + 41943040);        // 10.49 MB
  u16* qkv_b = (u16*)(ws + 52428800);       // 33.55 MB
  u16* kn = (u16*)(ws + 85983232);          // 8.39 MB
  u16* vt = (u16*)(ws + 94371840);          // 8.39 MB   (total 102.76 MB)
  u16* qn = wqkv_b;                         // reuse
  u16* attn = hs_b;                         // reuse

  cvt_bf16<<<5120, 256, 0, stream>>>(hs, hs_b, 1310720);
  cvt_bf16<<<5120, 256, 0, stream>>>(wqkv, wqkv_b, 1310720);
  cvt_bf16<<<2560, 256, 0, stream>>>(wo, wo_b, 655360);
  gemm256<4096, 4096, 2560, 256, 1><<<256, 512, 0, stream>>>(hs_b, wqkv_b, qkv_b);
  norm_rope<<<12288, 256, 0, stream>>>(qkv_b, cosb, sinb, qw, kw, qn, kn);
  vtransp<<<dim3(32, 8), 256, 0, stream>>>(qkv_b, vt);
  attn_fwd<<<dim3(32, 8, 2), 256, 0, stream>>>(qn, kn, vt, attn);
  gemm256<4096, 2560, 2048, 128, 0><<<320, 512, 0, stream>>>(attn, wo_b, d_out);
}

// Round 9
// 420.406 us; speedup vs baseline: 1.4637x; 1.4637x over previous
//
#include <hip/hip_runtime.h>
#include <cstdint>
#include <cstddef>

#define T_TOK 4096
#define HIDDIM 2560
#define NH 8
#define NKV 4
#define HD 256
#define SEQ 2048
#define NBATCH 2
#define WIN 1024
#define NQKV 4096          // (8+2*4)*256
#define QSCALE 0.0625f     // 256^-0.5

typedef unsigned short u16;
typedef __attribute__((ext_vector_type(8))) __bf16 bf16x8;
typedef __attribute__((ext_vector_type(8))) u16 u16x8;
typedef __attribute__((ext_vector_type(4))) float f32x4;

__device__ __forceinline__ u16 f2bf(float f) {
  union { float f; uint32_t u; } x{f};
  uint32_t r = x.u + 0x7FFFu + ((x.u >> 16) & 1u);
  return (u16)(r >> 16);
}
__device__ __forceinline__ float bf2f(u16 h) {
  union { uint32_t u; float f; } x{((uint32_t)h) << 16};
  return x.f;
}
__device__ __forceinline__ void gload_lds16(const void* g, void* l) {
  __builtin_amdgcn_global_load_lds((const __attribute__((address_space(1))) unsigned int*)g,
                                   (__attribute__((address_space(3))) unsigned int*)l, 16, 0, 0);
}
template <int N>
__device__ __forceinline__ void vmcnt_wait() {
  if constexpr (N >= 8) asm volatile("s_waitcnt vmcnt(8)" ::: "memory");
  else if constexpr (N == 6) asm volatile("s_waitcnt vmcnt(6)" ::: "memory");
  else if constexpr (N == 4) asm volatile("s_waitcnt vmcnt(4)" ::: "memory");
  else if constexpr (N == 3) asm volatile("s_waitcnt vmcnt(3)" ::: "memory");
  else asm volatile("s_waitcnt vmcnt(0)" ::: "memory");
}

// ---------------- fp32 -> bf16 convert ----------------
__global__ void cvt_bf16(const float* __restrict__ in, u16* __restrict__ out, int n8) {
  int i = blockIdx.x * 256 + threadIdx.x;
  if (i >= n8) return;
  const f32x4* p = (const f32x4*)(in + (size_t)i * 8);
  f32x4 a = p[0], b = p[1];
  u16 o[8];
  o[0] = f2bf(a[0]); o[1] = f2bf(a[1]); o[2] = f2bf(a[2]); o[3] = f2bf(a[3]);
  o[4] = f2bf(b[0]); o[5] = f2bf(b[1]); o[6] = f2bf(b[2]); o[7] = f2bf(b[3]);
  *(u16x8*)(out + (size_t)i * 8) = *(const u16x8*)o;
}

// ---------------- GEMM 256x{256|128} tile, BK=32, 4-buffer counted-vmcnt pipeline
template <int M, int N, int K, int BN, int OUTBF16>
__global__ __launch_bounds__(512, 2) void gemm256(const u16* __restrict__ A,
                                                  const u16* __restrict__ Bt,
                                                  void* __restrict__ Cp) {
  constexpr int NT = K / 32;
  constexpr int BCH = BN * 4;
  constexpr int LPT = (1024 + BCH) / 512;
  constexpr int NREP = BN / 64;
  constexpr int BUFB = 16384 + BN * 64;
  __shared__ char smem[4 * BUFB];

  const int tid = threadIdx.x, lane = tid & 63, w = tid >> 6;
  const int wr = w >> 2, wc = w & 3, hi = lane >> 4, lo = lane & 15;
  const int hi16 = hi * 16;
  constexpr int TOT = (M / 256) * (N / BN);
  const int bid = blockIdx.x;
  const int wg = (bid & 7) * (TOT / 8) + (bid >> 3);
  const int m0 = (wg / (N / BN)) * 256;
  const int n0 = (wg % (N / BN)) * BN;

  f32x4 acc[8][NREP] = {};

  auto stage = [&](int tt, int bb) {
    const int k0 = tt * 32;
    char* base = smem + bb * BUFB;
#pragma unroll
    for (int it = 0; it < 2; ++it) {
      int c = tid + it * 512;
      int r = (c >> 2) ^ ((c >> 4) & 1);
      int h = (c & 3) ^ (r & 3);
      gload_lds16(A + (size_t)(m0 + r) * K + k0 + h * 8, base + c * 16);
    }
#pragma unroll
    for (int it = 0; it < BCH / 512; ++it) {
      int c = tid + it * 512;
      int r = (c >> 2) ^ ((c >> 4) & 1);
      int h = (c & 3) ^ (r & 3);
      gload_lds16(Bt + (size_t)(n0 + r) * K + k0 + h * 8, base + 16384 + c * 16);
    }
  };
  auto body = [&](int bb) {
    char* base = smem + bb * BUFB;
    bf16x8 a[8], b[NREP];
#pragma unroll
    for (int mi = 0; mi < 8; ++mi) {
      int r = wr * 128 + mi * 16 + lo;
      a[mi] = *(const bf16x8*)(base + ((r * 64 + hi16) ^ ((r & 7) << 4)));
    }
#pragma unroll
    for (int ni = 0; ni < NREP; ++ni) {
      int r = wc * (BN / 4) + ni * 16 + lo;
      b[ni] = *(const bf16x8*)(base + 16384 + ((r * 64 + hi16) ^ ((r & 7) << 4)));
    }
    __builtin_amdgcn_s_setprio(1);
#pragma unroll
    for (int mi = 0; mi < 8; ++mi)
#pragma unroll
      for (int ni = 0; ni < NREP; ++ni)
        acc[mi][ni] = __builtin_amdgcn_mfma_f32_16x16x32_bf16(a[mi], b[ni], acc[mi][ni], 0, 0, 0);
    __builtin_amdgcn_s_setprio(0);
  };

  stage(0, 0); stage(1, 1); stage(2, 2);
  vmcnt_wait<2 * LPT>();
  __builtin_amdgcn_s_barrier();
  int t = 0;
  for (; t < NT - 3; ++t) {
    stage(t + 3, (t + 3) & 3);
    body(t & 3);
    vmcnt_wait<2 * LPT>();
    __builtin_amdgcn_s_barrier();
  }
  body(t & 3); vmcnt_wait<LPT>(); __builtin_amdgcn_s_barrier(); ++t;
  body(t & 3); vmcnt_wait<0>();   __builtin_amdgcn_s_barrier(); ++t;
  body(t & 3);

#pragma unroll
  for (int mi = 0; mi < 8; ++mi)
#pragma unroll
    for (int ni = 0; ni < NREP; ++ni) {
      int row = m0 + wr * 128 + mi * 16 + hi * 4;
      int col = n0 + wc * (BN / 4) + ni * 16 + lo;
#pragma unroll
      for (int r = 0; r < 4; ++r) {
        if (OUTBF16)
          ((u16*)Cp)[(size_t)(row + r) * N + col] = f2bf(acc[mi][ni][r]);
        else
          ((float*)Cp)[(size_t)(row + r) * N + col] = acc[mi][ni][r];
      }
    }
}

// ---------------- fused RMSNorm + RoPE for q,k (scale folded into q) ----------------
__global__ void norm_rope(const u16* __restrict__ qkv, const float* __restrict__ cosb,
                          const float* __restrict__ sinb, const float* __restrict__ qw,
                          const float* __restrict__ kw, u16* __restrict__ qn,
                          u16* __restrict__ kn) {
  int gw = blockIdx.x * 4 + (threadIdx.x >> 6);
  int lane = threadIdx.x & 63;
  int t = gw / 12, hh = gw % 12;
  const u16* x = qkv + (size_t)t * NQKV + hh * HD;
  int d = lane * 2;
  float x1a = bf2f(x[d]), x1b = bf2f(x[d + 1]);
  float x2a = bf2f(x[d + 128]), x2b = bf2f(x[d + 129]);
  float ss = x1a * x1a + x1b * x1b + x2a * x2a + x2b * x2b;
#pragma unroll
  for (int off = 1; off < 64; off <<= 1) ss += __shfl_xor(ss, off, 64);
  float inv = rsqrtf(ss * (1.0f / 256.0f) + 1e-6f);
  const float* wp = (hh < 8) ? qw : kw;
  float c0 = cosb[t * 128 + d], c1 = cosb[t * 128 + d + 1];
  float s0 = sinb[t * 128 + d], s1 = sinb[t * 128 + d + 1];
  float sc = (hh < 8) ? QSCALE : 1.0f;
  float y1a = x1a * inv * wp[d], y1b = x1b * inv * wp[d + 1];
  float y2a = x2a * inv * wp[d + 128], y2b = x2b * inv * wp[d + 129];
  float o1a = (y1a * c0 - y2a * s0) * sc, o1b = (y1b * c1 - y2b * s1) * sc;
  float o2a = (y2a * c0 + y1a * s0) * sc, o2b = (y2b * c1 + y1b * s1) * sc;
  u16* o = (hh < 8) ? (qn + ((size_t)t * 8 + hh) * HD) : (kn + ((size_t)t * 4 + (hh - 8)) * HD);
  ushort2 lo2, hi2;
  lo2.x = f2bf(o1a); lo2.y = f2bf(o1b);
  hi2.x = f2bf(o2a); hi2.y = f2bf(o2b);
  *(ushort2*)&o[d] = lo2;
  *(ushort2*)&o[d + 128] = hi2;
}

// ---------------- V transpose: qkv v-slice -> vt[b][kv][d][s] ----------------
__global__ void vtransp(const u16* __restrict__ qkv, u16* __restrict__ vt) {
  const int b = blockIdx.y >> 2, kv = blockIdx.y & 3;
  const int s0 = blockIdx.x * 64;
  const int t = threadIdx.x;
  __shared__ u16 tile[64 * 64];
  for (int d0 = 0; d0 < 256; d0 += 64) {
#pragma unroll
    for (int it = 0; it < 2; ++it) {
      int c = t + it * 256;
      int sr = c >> 3, dc = (c & 7) * 8;
      bf16x8 v = *(const bf16x8*)&qkv[(size_t)(b * SEQ + s0 + sr) * NQKV + 3072 + kv * HD + d0 + dc];
      *(bf16x8*)((char*)tile + ((sr * 128 + dc * 2) ^ ((sr & 7) << 4))) = v;
    }
    __syncthreads();
#pragma unroll
    for (int it = 0; it < 2; ++it) {
      int c = t + it * 256;
      int dr = c >> 3, sc0 = (c & 7) * 8;
      union { u16 a[8]; bf16x8 v; } u;
#pragma unroll
      for (int j = 0; j < 8; ++j) {
        int s = sc0 + j;
        u.a[j] = *(const u16*)((char*)tile + ((s * 128 + dr * 2) ^ ((s & 7) << 4)));
      }
      *(bf16x8*)&vt[((size_t)(b * 4 + kv) * 256 + d0 + dr) * SEQ + s0 + sc0] = u.v;
    }
    __syncthreads();
  }
}

// ---------------- flash attention, sliding window, GQA ----------------
// R7 compute body (KVBLK=32, mask every tile) + double-buffered K/V LDS +
// global_load_lds staging with pre-swizzled source (zero reg cost), issued
// before QK^T; single end-of-iter __syncthreads (vmcnt drain) completes it.
__global__ __launch_bounds__(256, 2) void attn_fwd(const u16* __restrict__ qn,
                                                   const u16* __restrict__ kn,
                                                   const u16* __restrict__ vt,
                                                   u16* __restrict__ aout) {
  const int qt = blockIdx.x * 64, h = blockIdx.y, b = blockIdx.z;
  const int kvh = h >> 1;
  const int t = threadIdx.x, lane = t & 63, w = t >> 6, hi = lane >> 4, lo = lane & 15;
  __shared__ u16 Ks[2][32 * 256];  // [k][d] swz byte^((k&7)<<4), 16KB each
  __shared__ u16 Vs[2][256 * 32];  // [d][k] swz byte^((d&7)<<4), 16KB each
  __shared__ u16 Ps[4][16 * 32];   // per-wave [q][k] swz byte^((q&7)<<4)

  bf16x8 qf[8];
  const int qrow = qt + w * 16 + lo;
#pragma unroll
  for (int dd = 0; dd < 8; ++dd)
    qf[dd] = *(const bf16x8*)&qn[((size_t)(b * SEQ + qrow) * 8 + h) * HD + dd * 32 + hi * 8];

  f32x4 oacc[16] = {};
  float mrow[4] = {-3e38f, -3e38f, -3e38f, -3e38f};
  float lrow[4] = {0.f, 0.f, 0.f, 0.f};
  const int kstart = qt >= WIN ? qt - WIN : 0;
  const int irow = qt + w * 16 + hi * 4;

  // stage K/V tile into buffer bb via global_load_lds, source pre-swizzled
  // to the inverse of the read swizzle (LDS dest linear).
  auto stage = [&](int kt2, int bb) {
#pragma unroll
    for (int it = 0; it < 4; ++it) {       // K: 1024 chunks of 16B
      int s = t + it * 256;
      int kr = s >> 5, ch = (s & 31) ^ (kr & 7);
      gload_lds16(kn + ((size_t)(b * SEQ + kt2 + kr) * 4 + kvh) * HD + ch * 8,
                  (char*)Ks[bb] + s * 16);
    }
#pragma unroll
    for (int it = 0; it < 4; ++it) {       // V: 1024 chunks of 16B
      int s = t + it * 256;
      int rp = s >> 2;
      int dr = rp ^ ((rp >> 2) & 1);       // inverse of row-bit-crossing XOR
      int ch = (s & 3) ^ (dr & 3);
      gload_lds16(vt + ((size_t)(b * 4 + kvh) * 256 + dr) * SEQ + kt2 + ch * 8,
                  (char*)Vs[bb] + s * 16);
    }
  };

  stage(kstart, 0);
  __syncthreads();
  int cur = 0;

  for (int kt = kstart; kt < qt + 64; kt += 32) {
    const bool more = (kt + 32) < (qt + 64);
    if (more) stage(kt + 32, cur ^ 1);     // async; completes at end barrier
    // QK^T : S[q=hi*4+r][key=kk*16+lo]
    f32x4 sacc[2];
#pragma unroll
    for (int kk = 0; kk < 2; ++kk) {
      f32x4 sa = {0.f, 0.f, 0.f, 0.f};
      int krow = kk * 16 + lo;
#pragma unroll
      for (int dd = 0; dd < 8; ++dd) {
        bf16x8 kf = *(const bf16x8*)((char*)Ks[cur] + ((krow * 512 + (dd * 32 + hi * 8) * 2) ^ ((krow & 7) << 4)));
        sa = __builtin_amdgcn_mfma_f32_16x16x32_bf16(qf[dd], kf, sa, 0, 0, 0);
      }
      sacc[kk] = sa;
    }
    // mask + online softmax (mask every tile — proven R7 logic)
    float pe[2][4];
    float tmax[4] = {-3e38f, -3e38f, -3e38f, -3e38f};
#pragma unroll
    for (int kk = 0; kk < 2; ++kk)
#pragma unroll
      for (int r = 0; r < 4; ++r) {
        int i = irow + r, j = kt + kk * 16 + lo;
        bool ok = (j <= i) && (i - j < WIN);
        float sv = ok ? sacc[kk][r] : -3e38f;
        sacc[kk][r] = sv;
        tmax[r] = fmaxf(tmax[r], sv);
      }
#pragma unroll
    for (int off = 1; off < 16; off <<= 1)
#pragma unroll
      for (int r = 0; r < 4; ++r) tmax[r] = fmaxf(tmax[r], __shfl_xor(tmax[r], off, 64));
    float scl[4], tsum[4];
#pragma unroll
    for (int r = 0; r < 4; ++r) {
      float mnew = fmaxf(mrow[r], tmax[r]);
      scl[r] = __expf(mrow[r] - mnew);
      mrow[r] = mnew;
      tsum[r] = 0.f;
    }
#pragma unroll
    for (int kk = 0; kk < 2; ++kk)
#pragma unroll
      for (int r = 0; r < 4; ++r) {
        float sv = sacc[kk][r];
        float p = (sv <= -1e37f) ? 0.f : __expf(sv - mrow[r]);
        pe[kk][r] = p;
        tsum[r] += p;
      }
#pragma unroll
    for (int off = 1; off < 16; off <<= 1)
#pragma unroll
      for (int r = 0; r < 4; ++r) tsum[r] += __shfl_xor(tsum[r], off, 64);
#pragma unroll
    for (int r = 0; r < 4; ++r) lrow[r] = lrow[r] * scl[r] + tsum[r];
#pragma unroll
    for (int dt = 0; dt < 16; ++dt)
#pragma unroll
      for (int r = 0; r < 4; ++r) oacc[dt][r] *= scl[r];
    // write P to per-wave LDS (same-wave write->read)
#pragma unroll
    for (int kk = 0; kk < 2; ++kk)
#pragma unroll
      for (int r = 0; r < 4; ++r) {
        int q = hi * 4 + r, cc = kk * 16 + lo;
        *(u16*)((char*)&Ps[w][0] + ((q * 64 + cc * 2) ^ ((q & 7) << 4))) = f2bf(pe[kk][r]);
      }
    // PV
    bf16x8 pf = *(const bf16x8*)((char*)&Ps[w][0] + ((lo * 64 + hi * 16) ^ ((lo & 7) << 4)));
#pragma unroll
    for (int dt = 0; dt < 16; ++dt) {
      int d = dt * 16 + lo;
      bf16x8 vf = *(const bf16x8*)((char*)Vs[cur] + ((d * 64 + hi * 16) ^ ((d & 7) << 4)));
      oacc[dt] = __builtin_amdgcn_mfma_f32_16x16x32_bf16(pf, vf, oacc[dt], 0, 0, 0);
    }
    __syncthreads();   // drains vmcnt: staged tile complete & visible
    cur ^= 1;
  }
  // epilogue
#pragma unroll
  for (int dt = 0; dt < 16; ++dt)
#pragma unroll
    for (int r = 0; r < 4; ++r) {
      int i = irow + r;
      aout[(size_t)(b * SEQ + i) * 2048 + h * HD + dt * 16 + lo] = f2bf(oacc[dt][r] / lrow[r]);
    }
}

extern "C" void kernel_launch(void* const* d_in, const int* in_sizes, int n_in,
                              void* d_out, int out_size, void* d_ws, size_t ws_size,
                              hipStream_t stream) {
  const float* hs = (const float*)d_in[0];
  const float* cosb = (const float*)d_in[1];
  const float* sinb = (const float*)d_in[2];
  const float* wqkv = (const float*)d_in[3];
  const float* qw = (const float*)d_in[4];
  const float* kw = (const float*)d_in[5];
  const float* wo = (const float*)d_in[6];
  char* ws = (char*)d_ws;
  u16* hs_b = (u16*)(ws);                   // 20.97 MB   [dead after GEMM1]
  u16* wqkv_b = (u16*)(ws + 20971520);      // 20.97 MB   [dead after GEMM1]
  u16* wo_b = (u16*)(ws + 41943040);        // 10.49 MB
  u16* qkv_b = (u16*)(ws + 52428800);       // 33.55 MB
  u16* kn = (u16*)(ws + 85983232);          // 8.39 MB
  u16* vt = (u16*)(ws + 94371840);          // 8.39 MB   (total 102.76 MB)
  u16* qn = wqkv_b;                         // reuse
  u16* attn = hs_b;                         // reuse

  cvt_bf16<<<5120, 256, 0, stream>>>(hs, hs_b, 1310720);
  cvt_bf16<<<5120, 256, 0, stream>>>(wqkv, wqkv_b, 1310720);
  cvt_bf16<<<2560, 256, 0, stream>>>(wo, wo_b, 655360);
  gemm256<4096, 4096, 2560, 256, 1><<<256, 512, 0, stream>>>(hs_b, wqkv_b, qkv_b);
  norm_rope<<<12288, 256, 0, stream>>>(qkv_b, cosb, sinb, qw, kw, qn, kn);
  vtransp<<<dim3(32, 8), 256, 0, stream>>>(qkv_b, vt);
  attn_fwd<<<dim3(32, 8, 2), 256, 0, stream>>>(qn, kn, vt, attn);
  gemm256<4096, 2560, 2048, 128, 0><<<320, 512, 0, stream>>>(attn, wo_b, d_out);
}

// Round 10
// 419.802 us; speedup vs baseline: 1.4658x; 1.0014x over previous
//
#include <hip/hip_runtime.h>
#include <cstdint>
#include <cstddef>

#define T_TOK 4096
#define HIDDIM 2560
#define NH 8
#define NKV 4
#define HD 256
#define SEQ 2048
#define NBATCH 2
#define WIN 1024
#define NQKV 4096          // (8+2*4)*256
#define QSCALE 0.0625f     // 256^-0.5

typedef unsigned short u16;
typedef __attribute__((ext_vector_type(8))) __bf16 bf16x8;
typedef __attribute__((ext_vector_type(8))) u16 u16x8;
typedef __attribute__((ext_vector_type(4))) float f32x4;

__device__ __forceinline__ u16 f2bf(float f) {
  union { float f; uint32_t u; } x{f};
  uint32_t r = x.u + 0x7FFFu + ((x.u >> 16) & 1u);
  return (u16)(r >> 16);
}
__device__ __forceinline__ float bf2f(u16 h) {
  union { uint32_t u; float f; } x{((uint32_t)h) << 16};
  return x.f;
}
__device__ __forceinline__ void gload_lds16(const void* g, void* l) {
  __builtin_amdgcn_global_load_lds((const __attribute__((address_space(1))) unsigned int*)g,
                                   (__attribute__((address_space(3))) unsigned int*)l, 16, 0, 0);
}
template <int N>
__device__ __forceinline__ void vmcnt_wait() {
  if constexpr (N >= 8) asm volatile("s_waitcnt vmcnt(8)" ::: "memory");
  else if constexpr (N == 6) asm volatile("s_waitcnt vmcnt(6)" ::: "memory");
  else if constexpr (N == 4) asm volatile("s_waitcnt vmcnt(4)" ::: "memory");
  else if constexpr (N == 3) asm volatile("s_waitcnt vmcnt(3)" ::: "memory");
  else asm volatile("s_waitcnt vmcnt(0)" ::: "memory");
}

// ---------------- fused fp32 -> bf16 convert (hs | wqkv | wo), outputs contiguous in ws
__global__ void cvt_all(const float* __restrict__ hs, const float* __restrict__ wqkv,
                        const float* __restrict__ wo, u16* __restrict__ out) {
  int i = blockIdx.x * 256 + threadIdx.x;   // 0..3276799
  const float* src;
  int off;
  if (i < 1310720)      { src = hs;   off = i; }
  else if (i < 2621440) { src = wqkv; off = i - 1310720; }
  else                  { src = wo;   off = i - 2621440; }
  const f32x4* p = (const f32x4*)(src + (size_t)off * 8);
  f32x4 a = p[0], b = p[1];
  u16 o[8];
  o[0] = f2bf(a[0]); o[1] = f2bf(a[1]); o[2] = f2bf(a[2]); o[3] = f2bf(a[3]);
  o[4] = f2bf(b[0]); o[5] = f2bf(b[1]); o[6] = f2bf(b[2]); o[7] = f2bf(b[3]);
  *(u16x8*)(out + (size_t)i * 8) = *(const u16x8*)o;
}

// ---------------- GEMM 256x{256|128} tile, BK=32, 4-buffer depth-3 pipeline,
// fine 2-phase body (T3): per phase {stage-half, 4-8 ds_read, barrier, setprio,
// 16(8) MFMA, setprio, barrier}; counted vmcnt once per K-tile (proven position).
template <int M, int N, int K, int BN, int OUTBF16>
__global__ __launch_bounds__(512, 2) void gemm256(const u16* __restrict__ A,
                                                  const u16* __restrict__ Bt,
                                                  void* __restrict__ Cp) {
  constexpr int NT = K / 32;
  constexpr int BCH = BN * 4;
  constexpr int LPT = (1024 + BCH) / 512;
  constexpr int NREP = BN / 64;
  constexpr int BUFB = 16384 + BN * 64;
  __shared__ char smem[4 * BUFB];

  const int tid = threadIdx.x, lane = tid & 63, w = tid >> 6;
  const int wr = w >> 2, wc = w & 3, hi = lane >> 4, lo = lane & 15;
  const int hi16 = hi * 16;
  constexpr int TOT = (M / 256) * (N / BN);
  const int bid = blockIdx.x;
  const int wg = (bid & 7) * (TOT / 8) + (bid >> 3);
  const int m0 = (wg / (N / BN)) * 256;
  const int n0 = (wg % (N / BN)) * BN;

  f32x4 acc[8][NREP] = {};

  auto stageA = [&](int tt, int bb) {
    const int k0 = tt * 32;
    char* base = smem + bb * BUFB;
#pragma unroll
    for (int it = 0; it < 2; ++it) {
      int c = tid + it * 512;
      int r = (c >> 2) ^ ((c >> 4) & 1);
      int h = (c & 3) ^ (r & 3);
      gload_lds16(A + (size_t)(m0 + r) * K + k0 + h * 8, base + c * 16);
    }
  };
  auto stageB = [&](int tt, int bb) {
    const int k0 = tt * 32;
    char* base = smem + bb * BUFB;
#pragma unroll
    for (int it = 0; it < BCH / 512; ++it) {
      int c = tid + it * 512;
      int r = (c >> 2) ^ ((c >> 4) & 1);
      int h = (c & 3) ^ (r & 3);
      gload_lds16(Bt + (size_t)(n0 + r) * K + k0 + h * 8, base + 16384 + c * 16);
    }
  };

  // wmode: 0 -> vmcnt(2*LPT), 1 -> vmcnt(LPT), 2 -> vmcnt(0)
  auto body = [&](int bb, int tt, int wmode) {
    char* base = smem + bb * BUFB;
    bf16x8 a[8], b[NREP];
    // ---- phase 1: stage A-half of tile tt, read a0..3 + all b, 16 MFMA
    if (tt >= 0) stageA(tt, tt & 3);
#pragma unroll
    for (int mi = 0; mi < 4; ++mi) {
      int r = wr * 128 + mi * 16 + lo;
      a[mi] = *(const bf16x8*)(base + ((r * 64 + hi16) ^ ((r & 7) << 4)));
    }
#pragma unroll
    for (int ni = 0; ni < NREP; ++ni) {
      int r = wc * (BN / 4) + ni * 16 + lo;
      b[ni] = *(const bf16x8*)(base + 16384 + ((r * 64 + hi16) ^ ((r & 7) << 4)));
    }
    __builtin_amdgcn_s_barrier();
    __builtin_amdgcn_s_setprio(1);
#pragma unroll
    for (int mi = 0; mi < 4; ++mi)
#pragma unroll
      for (int ni = 0; ni < NREP; ++ni)
        acc[mi][ni] = __builtin_amdgcn_mfma_f32_16x16x32_bf16(a[mi], b[ni], acc[mi][ni], 0, 0, 0);
    __builtin_amdgcn_s_setprio(0);
    __builtin_amdgcn_s_barrier();
    // ---- phase 2: stage B-half of tile tt, read a4..7, K-tile vmcnt, 16 MFMA
    if (tt >= 0) stageB(tt, tt & 3);
#pragma unroll
    for (int mi = 4; mi < 8; ++mi) {
      int r = wr * 128 + mi * 16 + lo;
      a[mi] = *(const bf16x8*)(base + ((r * 64 + hi16) ^ ((r & 7) << 4)));
    }
    if (wmode == 0) vmcnt_wait<2 * LPT>();
    else if (wmode == 1) vmcnt_wait<LPT>();
    else vmcnt_wait<0>();
    __builtin_amdgcn_s_barrier();
    __builtin_amdgcn_s_setprio(1);
#pragma unroll
    for (int mi = 4; mi < 8; ++mi)
#pragma unroll
      for (int ni = 0; ni < NREP; ++ni)
        acc[mi][ni] = __builtin_amdgcn_mfma_f32_16x16x32_bf16(a[mi], b[ni], acc[mi][ni], 0, 0, 0);
    __builtin_amdgcn_s_setprio(0);
    __builtin_amdgcn_s_barrier();
  };

  // prologue: 3 tiles in flight, tile0 complete
  stageA(0, 0); stageB(0, 0);
  stageA(1, 1); stageB(1, 1);
  stageA(2, 2); stageB(2, 2);
  vmcnt_wait<2 * LPT>();
  __builtin_amdgcn_s_barrier();
  int t = 0;
  for (; t < NT - 3; ++t) body(t & 3, t + 3, 0);
  body(t & 3, -1, 1); ++t;
  body(t & 3, -1, 2); ++t;
  body(t & 3, -1, 2);

#pragma unroll
  for (int mi = 0; mi < 8; ++mi)
#pragma unroll
    for (int ni = 0; ni < NREP; ++ni) {
      int row = m0 + wr * 128 + mi * 16 + hi * 4;
      int col = n0 + wc * (BN / 4) + ni * 16 + lo;
#pragma unroll
      for (int r = 0; r < 4; ++r) {
        if (OUTBF16)
          ((u16*)Cp)[(size_t)(row + r) * N + col] = f2bf(acc[mi][ni][r]);
        else
          ((float*)Cp)[(size_t)(row + r) * N + col] = acc[mi][ni][r];
      }
    }
}

// ---------------- fused RMSNorm+RoPE (blocks 0..12287) + V transpose (12288..12543)
__global__ void normvt(const u16* __restrict__ qkv, const float* __restrict__ cosb,
                       const float* __restrict__ sinb, const float* __restrict__ qw,
                       const float* __restrict__ kw, u16* __restrict__ qn,
                       u16* __restrict__ kn, u16* __restrict__ vt) {
  __shared__ u16 tile[64 * 64];
  if (blockIdx.x < 12288) {
    int gw = blockIdx.x * 4 + (threadIdx.x >> 6);
    int lane = threadIdx.x & 63;
    int t = gw / 12, hh = gw % 12;
    const u16* x = qkv + (size_t)t * NQKV + hh * HD;
    int d = lane * 2;
    float x1a = bf2f(x[d]), x1b = bf2f(x[d + 1]);
    float x2a = bf2f(x[d + 128]), x2b = bf2f(x[d + 129]);
    float ss = x1a * x1a + x1b * x1b + x2a * x2a + x2b * x2b;
#pragma unroll
    for (int off = 1; off < 64; off <<= 1) ss += __shfl_xor(ss, off, 64);
    float inv = rsqrtf(ss * (1.0f / 256.0f) + 1e-6f);
    const float* wp = (hh < 8) ? qw : kw;
    float c0 = cosb[t * 128 + d], c1 = cosb[t * 128 + d + 1];
    float s0 = sinb[t * 128 + d], s1 = sinb[t * 128 + d + 1];
    float sc = (hh < 8) ? QSCALE : 1.0f;
    float y1a = x1a * inv * wp[d], y1b = x1b * inv * wp[d + 1];
    float y2a = x2a * inv * wp[d + 128], y2b = x2b * inv * wp[d + 129];
    float o1a = (y1a * c0 - y2a * s0) * sc, o1b = (y1b * c1 - y2b * s1) * sc;
    float o2a = (y2a * c0 + y1a * s0) * sc, o2b = (y2b * c1 + y1b * s1) * sc;
    u16* o = (hh < 8) ? (qn + ((size_t)t * 8 + hh) * HD) : (kn + ((size_t)t * 4 + (hh - 8)) * HD);
    ushort2 lo2, hi2;
    lo2.x = f2bf(o1a); lo2.y = f2bf(o1b);
    hi2.x = f2bf(o2a); hi2.y = f2bf(o2b);
    *(ushort2*)&o[d] = lo2;
    *(ushort2*)&o[d + 128] = hi2;
  } else {
    int bid2 = blockIdx.x - 12288;          // 0..255 = (32 s-tiles) x (8 bk)
    const int xb = bid2 & 31, yb = bid2 >> 5;
    const int b = yb >> 2, kv = yb & 3;
    const int s0 = xb * 64;
    const int t = threadIdx.x;
    for (int d0 = 0; d0 < 256; d0 += 64) {
#pragma unroll
      for (int it = 0; it < 2; ++it) {
        int c = t + it * 256;
        int sr = c >> 3, dc = (c & 7) * 8;
        bf16x8 v = *(const bf16x8*)&qkv[(size_t)(b * SEQ + s0 + sr) * NQKV + 3072 + kv * HD + d0 + dc];
        *(bf16x8*)((char*)tile + ((sr * 128 + dc * 2) ^ ((sr & 7) << 4))) = v;
      }
      __syncthreads();
#pragma unroll
      for (int it = 0; it < 2; ++it) {
        int c = t + it * 256;
        int dr = c >> 3, sc0 = (c & 7) * 8;
        union { u16 a[8]; bf16x8 v; } u;
#pragma unroll
        for (int j = 0; j < 8; ++j) {
          int s = sc0 + j;
          u.a[j] = *(const u16*)((char*)tile + ((s * 128 + dr * 2) ^ ((s & 7) << 4)));
        }
        *(bf16x8*)&vt[((size_t)(b * 4 + kv) * 256 + d0 + dr) * SEQ + s0 + sc0] = u.v;
      }
      __syncthreads();
    }
  }
}

// ---------------- flash attention, sliding window, GQA ----------------
// R9 structure + wave-uniform needmask fast path (mask only 2 causal-edge and
// 2 window-edge tiles; ~30/34 iters skip mask VALU and exp guard).
__global__ __launch_bounds__(256, 2) void attn_fwd(const u16* __restrict__ qn,
                                                   const u16* __restrict__ kn,
                                                   const u16* __restrict__ vt,
                                                   u16* __restrict__ aout) {
  const int qt = blockIdx.x * 64, h = blockIdx.y, b = blockIdx.z;
  const int kvh = h >> 1;
  const int t = threadIdx.x, lane = t & 63, w = t >> 6, hi = lane >> 4, lo = lane & 15;
  __shared__ u16 Ks[2][32 * 256];
  __shared__ u16 Vs[2][256 * 32];
  __shared__ u16 Ps[4][16 * 32];

  bf16x8 qf[8];
  const int qrow = qt + w * 16 + lo;
#pragma unroll
  for (int dd = 0; dd < 8; ++dd)
    qf[dd] = *(const bf16x8*)&qn[((size_t)(b * SEQ + qrow) * 8 + h) * HD + dd * 32 + hi * 8];

  f32x4 oacc[16] = {};
  float mrow[4] = {-3e38f, -3e38f, -3e38f, -3e38f};
  float lrow[4] = {0.f, 0.f, 0.f, 0.f};
  const int kstart = qt >= WIN ? qt - WIN : 0;
  const int irow = qt + w * 16 + hi * 4;

  auto stage = [&](int kt2, int bb) {
#pragma unroll
    for (int it = 0; it < 4; ++it) {
      int s = t + it * 256;
      int kr = s >> 5, ch = (s & 31) ^ (kr & 7);
      gload_lds16(kn + ((size_t)(b * SEQ + kt2 + kr) * 4 + kvh) * HD + ch * 8,
                  (char*)Ks[bb] + s * 16);
    }
#pragma unroll
    for (int it = 0; it < 4; ++it) {
      int s = t + it * 256;
      int rp = s >> 2;
      int dr = rp ^ ((rp >> 2) & 1);
      int ch = (s & 3) ^ (dr & 3);
      gload_lds16(vt + ((size_t)(b * 4 + kvh) * 256 + dr) * SEQ + kt2 + ch * 8,
                  (char*)Vs[bb] + s * 16);
    }
  };

  stage(kstart, 0);
  __syncthreads();
  int cur = 0;

  for (int kt = kstart; kt < qt + 64; kt += 32) {
    const bool more = (kt + 32) < (qt + 64);
    if (more) stage(kt + 32, cur ^ 1);
    // QK^T
    f32x4 sacc[2];
#pragma unroll
    for (int kk = 0; kk < 2; ++kk) {
      f32x4 sa = {0.f, 0.f, 0.f, 0.f};
      int krow = kk * 16 + lo;
#pragma unroll
      for (int dd = 0; dd < 8; ++dd) {
        bf16x8 kf = *(const bf16x8*)((char*)Ks[cur] + ((krow * 512 + (dd * 32 + hi * 8) * 2) ^ ((krow & 7) << 4)));
        sa = __builtin_amdgcn_mfma_f32_16x16x32_bf16(qf[dd], kf, sa, 0, 0, 0);
      }
      sacc[kk] = sa;
    }
    // mask only edge tiles (wave-uniform)
    const bool needmask = (kt + 32 > qt) || (qt >= WIN && kt < kstart + 64);
    float pe[2][4];
    float tmax[4] = {-3e38f, -3e38f, -3e38f, -3e38f};
    if (needmask) {
#pragma unroll
      for (int kk = 0; kk < 2; ++kk)
#pragma unroll
        for (int r = 0; r < 4; ++r) {
          int i = irow + r, j = kt + kk * 16 + lo;
          bool ok = (j <= i) && (i - j < WIN);
          float sv = ok ? sacc[kk][r] : -3e38f;
          sacc[kk][r] = sv;
          tmax[r] = fmaxf(tmax[r], sv);
        }
    } else {
#pragma unroll
      for (int kk = 0; kk < 2; ++kk)
#pragma unroll
        for (int r = 0; r < 4; ++r) tmax[r] = fmaxf(tmax[r], sacc[kk][r]);
    }
#pragma unroll
    for (int off = 1; off < 16; off <<= 1)
#pragma unroll
      for (int r = 0; r < 4; ++r) tmax[r] = fmaxf(tmax[r], __shfl_xor(tmax[r], off, 64));
    float scl[4], tsum[4];
#pragma unroll
    for (int r = 0; r < 4; ++r) {
      float mnew = fmaxf(mrow[r], tmax[r]);
      scl[r] = __expf(mrow[r] - mnew);
      mrow[r] = mnew;
      tsum[r] = 0.f;
    }
    if (needmask) {
#pragma unroll
      for (int kk = 0; kk < 2; ++kk)
#pragma unroll
        for (int r = 0; r < 4; ++r) {
          float sv = sacc[kk][r];
          float p = (sv <= -1e37f) ? 0.f : __expf(sv - mrow[r]);
          pe[kk][r] = p;
          tsum[r] += p;
        }
    } else {
#pragma unroll
      for (int kk = 0; kk < 2; ++kk)
#pragma unroll
        for (int r = 0; r < 4; ++r) {
          float p = __expf(sacc[kk][r] - mrow[r]);
          pe[kk][r] = p;
          tsum[r] += p;
        }
    }
#pragma unroll
    for (int off = 1; off < 16; off <<= 1)
#pragma unroll
      for (int r = 0; r < 4; ++r) tsum[r] += __shfl_xor(tsum[r], off, 64);
#pragma unroll
    for (int r = 0; r < 4; ++r) lrow[r] = lrow[r] * scl[r] + tsum[r];
#pragma unroll
    for (int dt = 0; dt < 16; ++dt)
#pragma unroll
      for (int r = 0; r < 4; ++r) oacc[dt][r] *= scl[r];
#pragma unroll
    for (int kk = 0; kk < 2; ++kk)
#pragma unroll
      for (int r = 0; r < 4; ++r) {
        int q = hi * 4 + r, cc = kk * 16 + lo;
        *(u16*)((char*)&Ps[w][0] + ((q * 64 + cc * 2) ^ ((q & 7) << 4))) = f2bf(pe[kk][r]);
      }
    bf16x8 pf = *(const bf16x8*)((char*)&Ps[w][0] + ((lo * 64 + hi * 16) ^ ((lo & 7) << 4)));
#pragma unroll
    for (int dt = 0; dt < 16; ++dt) {
      int d = dt * 16 + lo;
      bf16x8 vf = *(const bf16x8*)((char*)Vs[cur] + ((d * 64 + hi * 16) ^ ((d & 7) << 4)));
      oacc[dt] = __builtin_amdgcn_mfma_f32_16x16x32_bf16(pf, vf, oacc[dt], 0, 0, 0);
    }
    __syncthreads();
    cur ^= 1;
  }
#pragma unroll
  for (int dt = 0; dt < 16; ++dt)
#pragma unroll
    for (int r = 0; r < 4; ++r) {
      int i = irow + r;
      aout[(size_t)(b * SEQ + i) * 2048 + h * HD + dt * 16 + lo] = f2bf(oacc[dt][r] / lrow[r]);
    }
}

extern "C" void kernel_launch(void* const* d_in, const int* in_sizes, int n_in,
                              void* d_out, int out_size, void* d_ws, size_t ws_size,
                              hipStream_t stream) {
  const float* hs = (const float*)d_in[0];
  const float* cosb = (const float*)d_in[1];
  const float* sinb = (const float*)d_in[2];
  const float* wqkv = (const float*)d_in[3];
  const float* qw = (const float*)d_in[4];
  const float* kw = (const float*)d_in[5];
  const float* wo = (const float*)d_in[6];
  char* ws = (char*)d_ws;
  u16* hs_b = (u16*)(ws);                   // 20.97 MB   [dead after GEMM1]
  u16* wqkv_b = (u16*)(ws + 20971520);      // 20.97 MB   [dead after GEMM1]
  u16* wo_b = (u16*)(ws + 41943040);        // 10.49 MB
  u16* qkv_b = (u16*)(ws + 52428800);       // 33.55 MB
  u16* kn = (u16*)(ws + 85983232);          // 8.39 MB
  u16* vt = (u16*)(ws + 94371840);          // 8.39 MB   (total 102.76 MB)
  u16* qn = wqkv_b;                         // reuse
  u16* attn = hs_b;                         // reuse

  cvt_all<<<12800, 256, 0, stream>>>(hs, wqkv, wo, (u16*)ws);
  gemm256<4096, 4096, 2560, 256, 1><<<256, 512, 0, stream>>>(hs_b, wqkv_b, qkv_b);
  normvt<<<12544, 256, 0, stream>>>(qkv_b, cosb, sinb, qw, kw, qn, kn, vt);
  attn_fwd<<<dim3(32, 8, 2), 256, 0, stream>>>(qn, kn, vt, attn);
  gemm256<4096, 2560, 2048, 128, 0><<<320, 512, 0, stream>>>(attn, wo_b, d_out);
}